// Round 1
// baseline (869.756 us; speedup 1.0000x reference)
//
#include <hip/hip_runtime.h>
#include <cstdint>
#include <cstddef>

#define BB 2
#define SS 2048
#define DD 1024
#define HH 16
#define DKK 64

typedef __attribute__((ext_vector_type(8))) short short8x;
typedef __attribute__((ext_vector_type(4))) float f32x4;

__device__ __forceinline__ unsigned short f2b(float f) {
  union { float f; unsigned u; } v; v.f = f;
  unsigned r = (v.u + 0x7fffu + ((v.u >> 16) & 1u)) >> 16;  // RNE
  return (unsigned short)r;
}

__device__ __forceinline__ f32x4 mfma16(short8x a, short8x b, f32x4 c) {
  return __builtin_amdgcn_mfma_f32_16x16x32_bf16(a, b, c, 0, 0, 0);
}

__device__ __forceinline__ short8x negbf(short8x a) {
  short8x r;
#pragma unroll
  for (int j = 0; j < 8; j++) r[j] = (short)(a[j] ^ (short)0x8000);
  return r;
}

// ---------------- pack weights: WcatT[5120][2048] = [[Wq_r,Wq_i,Wk_r,Wk_i,Wv],[-Wq_i,Wq_r,-Wk_i,Wk_r,0]]^T (bf16)
//                  WoT[1024][1024] = Wo^T (bf16)
__global__ void pack_w_kernel(const float* __restrict__ Wq_r, const float* __restrict__ Wq_i,
                              const float* __restrict__ Wk_r, const float* __restrict__ Wk_i,
                              const float* __restrict__ Wv, const float* __restrict__ Wo,
                              unsigned short* __restrict__ WcatT, unsigned short* __restrict__ WoT) {
  int gid = blockIdx.x * 256 + threadIdx.x;
  if (gid < 5120 * 2048) {
    int k = gid & 2047;
    int n = gid >> 11;
    int q = n >> 10, j = n & 1023;
    float v;
    if (k < 1024) {
      const float* src = (q == 0) ? Wq_r : (q == 1) ? Wq_i : (q == 2) ? Wk_r : (q == 3) ? Wk_i : Wv;
      v = src[k * 1024 + j];
    } else {
      int k2 = k - 1024;
      if (q == 0)      v = -Wq_i[k2 * 1024 + j];
      else if (q == 1) v =  Wq_r[k2 * 1024 + j];
      else if (q == 2) v = -Wk_i[k2 * 1024 + j];
      else if (q == 3) v =  Wk_r[k2 * 1024 + j];
      else             v = 0.0f;
    }
    WcatT[gid] = f2b(v);
  } else {
    int g2 = gid - 5120 * 2048;            // n*1024 + k
    int k = g2 & 1023, n = g2 >> 10;
    WoT[g2] = f2b(Wo[k * 1024 + n]);
  }
}

// ---------------- pack X: Xcat[4096][2048] = [z_real | z_imag] (bf16)
__global__ void pack_x_kernel(const float* __restrict__ zr, const float* __restrict__ zi,
                              unsigned short* __restrict__ X) {
  int gid = blockIdx.x * 256 + threadIdx.x;  // 4096*2048
  int k = gid & 2047, m = gid >> 11;
  float v = (k < 1024) ? zr[m * 1024 + k] : zi[m * 1024 + (k - 1024)];
  X[gid] = f2b(v);
}

// ---------------- projection GEMM: C = Xcat @ WcatT^T, M=4096 N=5120 K=2048; epilogue routes to Q/K (bf16,[BH][S][DK]) and V^T ([BH][DK][S])
__global__ __launch_bounds__(256, 2) void gemm_proj_kernel(
    const unsigned short* __restrict__ A, const unsigned short* __restrict__ Bt,
    unsigned short* __restrict__ Qr, unsigned short* __restrict__ Qi,
    unsigned short* __restrict__ Kr, unsigned short* __restrict__ Ki,
    unsigned short* __restrict__ VT) {
  constexpr int K = 2048;
  __shared__ __attribute__((aligned(16))) unsigned short As[128][40];
  __shared__ __attribute__((aligned(16))) unsigned short Bs[128][40];
  const int tid = threadIdx.x;
  const int m0 = blockIdx.x * 128;
  const int n0 = blockIdx.y * 128;
  const int lane = tid & 63, wid = tid >> 6;
  const int l15 = lane & 15, quad = lane >> 4;
  const int wm = (wid & 1) * 64, wn = (wid >> 1) * 64;
  const int lrow = tid >> 1, lseg = (tid & 1) * 16;
  f32x4 acc[4][4] = {};
  const int4* ga = (const int4*)(A + (size_t)(m0 + lrow) * K + lseg);
  const int4* gb = (const int4*)(Bt + (size_t)(n0 + lrow) * K + lseg);
  for (int k0 = 0; k0 < K; k0 += 32) {
    int4 a0 = ga[0], a1 = ga[1];
    int4 b0 = gb[0], b1 = gb[1];
    __syncthreads();
    *(int4*)&As[lrow][lseg] = a0;  *(int4*)&As[lrow][lseg + 8] = a1;
    *(int4*)&Bs[lrow][lseg] = b0;  *(int4*)&Bs[lrow][lseg + 8] = b1;
    __syncthreads();
    short8x af[4], bfr[4];
#pragma unroll
    for (int i = 0; i < 4; i++) af[i]  = *(const short8x*)&As[wm + i * 16 + l15][quad * 8];
#pragma unroll
    for (int i = 0; i < 4; i++) bfr[i] = *(const short8x*)&Bs[wn + i * 16 + l15][quad * 8];
#pragma unroll
    for (int mi = 0; mi < 4; mi++)
#pragma unroll
      for (int ni = 0; ni < 4; ni++)
        acc[mi][ni] = mfma16(af[mi], bfr[ni], acc[mi][ni]);
    ga += 4; gb += 4;
  }
#pragma unroll
  for (int mi = 0; mi < 4; mi++) {
#pragma unroll
    for (int ni = 0; ni < 4; ni++) {
      int gn = n0 + wn + ni * 16 + l15;
#pragma unroll
      for (int r = 0; r < 4; r++) {
        int gm = m0 + wm + mi * 16 + quad * 4 + r;
        int b = gm >> 11, s = gm & 2047;
        unsigned short bv = f2b(acc[mi][ni][r]);
        if (gn < 4096) {
          int which = gn >> 10, j = gn & 1023, h = j >> 6, dk = j & 63;
          unsigned short* dst = (which == 0) ? Qr : (which == 1) ? Qi : (which == 2) ? Kr : Ki;
          dst[(((size_t)(b * HH + h)) * SS + s) * DKK + dk] = bv;
        } else {
          int j = gn - 4096, h = j >> 6, dk = j & 63;
          VT[(((size_t)(b * HH + h)) * DKK + dk) * SS + s] = bv;
        }
      }
    }
  }
}

// ---------------- flash attention fwd: per (b,h,qtile=128); online softmax; writes ctx (bf16 [B][S][D]) and row m,l
__global__ __launch_bounds__(256, 2) void flash_kernel(
    const unsigned short* __restrict__ Qr, const unsigned short* __restrict__ Qi,
    const unsigned short* __restrict__ Kr, const unsigned short* __restrict__ Ki,
    const unsigned short* __restrict__ VT, const int* __restrict__ mask,
    unsigned short* __restrict__ ctx, float* __restrict__ Mrow, float* __restrict__ Lrow) {
  __shared__ __attribute__((aligned(16))) unsigned short KsR[64][72];
  __shared__ __attribute__((aligned(16))) unsigned short KsI[64][72];
  __shared__ __attribute__((aligned(16))) unsigned short Vs[64][72];
  __shared__ __attribute__((aligned(16))) unsigned short Ps[4][32][72];
  const int tid = threadIdx.x;
  const int lane = tid & 63, wid = tid >> 6;
  const int l15 = lane & 15, quad = lane >> 4;
  const int qt = blockIdx.x * 128;
  const int h = blockIdx.y, b = blockIdx.z;
  const size_t bhoff = (size_t)(b * HH + h) * SS * DKK;
  const float scale = 0.125f;
  // Q fragments for this wave's 32 rows (2 m-blocks x 2 k-steps), kept in regs
  short8x fqr[2][2], fqi[2][2], fqrn[2][2];
#pragma unroll
  for (int mb = 0; mb < 2; mb++) {
    int row = qt + wid * 32 + mb * 16 + l15;
#pragma unroll
    for (int ks = 0; ks < 2; ks++) {
      fqr[mb][ks] = *(const short8x*)(Qr + bhoff + (size_t)row * DKK + ks * 32 + quad * 8);
      fqi[mb][ks] = *(const short8x*)(Qi + bhoff + (size_t)row * DKK + ks * 32 + quad * 8);
      fqrn[mb][ks] = negbf(fqr[mb][ks]);
    }
  }
  const int srow = tid >> 2, sseg = (tid & 3) * 16;
  float mrun[2][4], lrun[2][4];
  f32x4 ctxacc[2][4] = {};
#pragma unroll
  for (int mb = 0; mb < 2; mb++)
#pragma unroll
    for (int r = 0; r < 4; r++) { mrun[mb][r] = -3.0e38f; lrun[mb][r] = 0.0f; }

  for (int kt = 0; kt < SS; kt += 64) {
    const int4* gkr = (const int4*)(Kr + bhoff + (size_t)(kt + srow) * DKK + sseg);
    const int4* gki = (const int4*)(Ki + bhoff + (size_t)(kt + srow) * DKK + sseg);
    const int4* gv  = (const int4*)(VT + bhoff + (size_t)srow * SS + kt + sseg);
    int4 kr0 = gkr[0], kr1 = gkr[1];
    int4 ki0 = gki[0], ki1 = gki[1];
    int4 v0 = gv[0],  v1 = gv[1];
    int mk[4];
#pragma unroll
    for (int nb = 0; nb < 4; nb++) mk[nb] = mask[b * SS + kt + nb * 16 + l15];
    __syncthreads();
    *(int4*)&KsR[srow][sseg] = kr0;  *(int4*)&KsR[srow][sseg + 8] = kr1;
    *(int4*)&KsI[srow][sseg] = ki0;  *(int4*)&KsI[srow][sseg + 8] = ki1;
    *(int4*)&Vs[srow][sseg]  = v0;   *(int4*)&Vs[srow][sseg + 8]  = v1;
    __syncthreads();
    // scores: Sr = QrKr^T + QiKi^T ; Si = QiKr^T - QrKi^T
    f32x4 asr[2][4], asi[2][4];
#pragma unroll
    for (int nb = 0; nb < 4; nb++) {
      short8x bkr0 = *(const short8x*)&KsR[nb * 16 + l15][quad * 8];
      short8x bkr1 = *(const short8x*)&KsR[nb * 16 + l15][32 + quad * 8];
      short8x bki0 = *(const short8x*)&KsI[nb * 16 + l15][quad * 8];
      short8x bki1 = *(const short8x*)&KsI[nb * 16 + l15][32 + quad * 8];
#pragma unroll
      for (int mb = 0; mb < 2; mb++) {
        f32x4 sr = {0.f, 0.f, 0.f, 0.f}, si = {0.f, 0.f, 0.f, 0.f};
        sr = mfma16(fqr[mb][0], bkr0, sr);  sr = mfma16(fqr[mb][1], bkr1, sr);
        sr = mfma16(fqi[mb][0], bki0, sr);  sr = mfma16(fqi[mb][1], bki1, sr);
        si = mfma16(fqi[mb][0], bkr0, si);  si = mfma16(fqi[mb][1], bkr1, si);
        si = mfma16(fqrn[mb][0], bki0, si); si = mfma16(fqrn[mb][1], bki1, si);
        asr[mb][nb] = sr; asi[mb][nb] = si;
      }
    }
    // hybrid score epilogue (in-place into asr)
#pragma unroll
    for (int mb = 0; mb < 2; mb++)
#pragma unroll
      for (int nb = 0; nb < 4; nb++)
#pragma unroll
        for (int r = 0; r < 4; r++) {
          float srv = asr[mb][nb][r] * scale;
          float siv = asi[mb][nb][r] * scale;
          float r2 = srv * srv + siv * siv;
          float inv = rsqrtf(r2);
          float sc = (r2 * inv + 0.3f * srv * inv) * scale;
          asr[mb][nb][r] = mk[nb] ? sc : -1e9f;
        }
    // online softmax update per row
#pragma unroll
    for (int mb = 0; mb < 2; mb++)
#pragma unroll
      for (int r = 0; r < 4; r++) {
        float rm = fmaxf(fmaxf(asr[mb][0][r], asr[mb][1][r]), fmaxf(asr[mb][2][r], asr[mb][3][r]));
#pragma unroll
        for (int off = 1; off < 16; off <<= 1) rm = fmaxf(rm, __shfl_xor(rm, off, 64));
        float mnew = fmaxf(mrun[mb][r], rm);
        float al = __expf(mrun[mb][r] - mnew);
        mrun[mb][r] = mnew;
        float ps = 0.f;
#pragma unroll
        for (int nb = 0; nb < 4; nb++) {
          float p = __expf(asr[mb][nb][r] - mnew);
          Ps[wid][mb * 16 + quad * 4 + r][nb * 16 + l15] = f2b(p);
          ps += p;
        }
#pragma unroll
        for (int off = 1; off < 16; off <<= 1) ps += __shfl_xor(ps, off, 64);
        lrun[mb][r] = lrun[mb][r] * al + ps;
#pragma unroll
        for (int db = 0; db < 4; db++) ctxacc[mb][db][r] *= al;
      }
    // PV: ctx += P @ V   (P from per-wave LDS in A-layout; V^T tile as B-operand)
#pragma unroll
    for (int ks = 0; ks < 2; ks++)
#pragma unroll
      for (int db = 0; db < 4; db++) {
        short8x bv = *(const short8x*)&Vs[db * 16 + l15][ks * 32 + quad * 8];
#pragma unroll
        for (int mb = 0; mb < 2; mb++) {
          short8x ap = *(const short8x*)&Ps[wid][mb * 16 + l15][ks * 32 + quad * 8];
          ctxacc[mb][db] = mfma16(ap, bv, ctxacc[mb][db]);
        }
      }
  }
  // finalize
#pragma unroll
  for (int mb = 0; mb < 2; mb++)
#pragma unroll
    for (int r = 0; r < 4; r++) {
      int s = qt + wid * 32 + mb * 16 + quad * 4 + r;
      float linv = 1.0f / lrun[mb][r];
#pragma unroll
      for (int db = 0; db < 4; db++)
        ctx[((size_t)b * SS + s) * DD + h * DKK + db * 16 + l15] = f2b(ctxacc[mb][db][r] * linv);
      if (l15 == 0) {
        Mrow[(size_t)(b * HH + h) * SS + s] = mrun[mb][r];
        Lrow[(size_t)(b * HH + h) * SS + s] = lrun[mb][r];
      }
    }
}

// ---------------- output GEMM: out = ctx @ WoT^T + bias, M=4096 N=1024 K=1024 (fp32 out)
__global__ __launch_bounds__(256, 2) void gemm_out_kernel(
    const unsigned short* __restrict__ A, const unsigned short* __restrict__ Bt,
    const float* __restrict__ bias, float* __restrict__ out) {
  constexpr int K = 1024;
  __shared__ __attribute__((aligned(16))) unsigned short As[128][40];
  __shared__ __attribute__((aligned(16))) unsigned short Bs[128][40];
  const int tid = threadIdx.x;
  const int m0 = blockIdx.x * 128;
  const int n0 = blockIdx.y * 128;
  const int lane = tid & 63, wid = tid >> 6;
  const int l15 = lane & 15, quad = lane >> 4;
  const int wm = (wid & 1) * 64, wn = (wid >> 1) * 64;
  const int lrow = tid >> 1, lseg = (tid & 1) * 16;
  f32x4 acc[4][4] = {};
  const int4* ga = (const int4*)(A + (size_t)(m0 + lrow) * K + lseg);
  const int4* gb = (const int4*)(Bt + (size_t)(n0 + lrow) * K + lseg);
  for (int k0 = 0; k0 < K; k0 += 32) {
    int4 a0 = ga[0], a1 = ga[1];
    int4 b0 = gb[0], b1 = gb[1];
    __syncthreads();
    *(int4*)&As[lrow][lseg] = a0;  *(int4*)&As[lrow][lseg + 8] = a1;
    *(int4*)&Bs[lrow][lseg] = b0;  *(int4*)&Bs[lrow][lseg + 8] = b1;
    __syncthreads();
    short8x af[4], bfr[4];
#pragma unroll
    for (int i = 0; i < 4; i++) af[i]  = *(const short8x*)&As[wm + i * 16 + l15][quad * 8];
#pragma unroll
    for (int i = 0; i < 4; i++) bfr[i] = *(const short8x*)&Bs[wn + i * 16 + l15][quad * 8];
#pragma unroll
    for (int mi = 0; mi < 4; mi++)
#pragma unroll
      for (int ni = 0; ni < 4; ni++)
        acc[mi][ni] = mfma16(af[mi], bfr[ni], acc[mi][ni]);
    ga += 4; gb += 4;
  }
#pragma unroll
  for (int mi = 0; mi < 4; mi++)
#pragma unroll
    for (int ni = 0; ni < 4; ni++) {
      int gn = n0 + wn + ni * 16 + l15;
      float bv = bias[gn];
#pragma unroll
      for (int r = 0; r < 4; r++) {
        int gm = m0 + wm + mi * 16 + quad * 4 + r;
        out[(size_t)gm * 1024 + gn] = acc[mi][ni][r] + bv;
      }
    }
}

// ---------------- probs_mean: recompute scores per (b, qtile=64, ktile=64) over all heads; probs via stored m,l; mean over H
__global__ __launch_bounds__(256, 2) void probsmean_kernel(
    const unsigned short* __restrict__ Qr, const unsigned short* __restrict__ Qi,
    const unsigned short* __restrict__ Kr, const unsigned short* __restrict__ Ki,
    const int* __restrict__ mask, const float* __restrict__ Mrow, const float* __restrict__ Lrow,
    float* __restrict__ out2) {
  __shared__ __attribute__((aligned(16))) unsigned short KsR[64][72];
  __shared__ __attribute__((aligned(16))) unsigned short KsI[64][72];
  const int tid = threadIdx.x, lane = tid & 63, wid = tid >> 6;
  const int l15 = lane & 15, quad = lane >> 4;
  const int qt = blockIdx.x * 64;
  const int kt = blockIdx.y * 64;
  const int b = blockIdx.z;
  const int qrow0 = qt + wid * 16;
  const int srow = tid >> 2, sseg = (tid & 3) * 16;
  const float scale = 0.125f;
  int mk[4];
#pragma unroll
  for (int nb = 0; nb < 4; nb++) mk[nb] = mask[b * SS + kt + nb * 16 + l15];
  float psum[4][4] = {};  // [nb][r]
  for (int h = 0; h < HH; h++) {
    const size_t bhoff = (size_t)(b * HH + h) * SS * DKK;
    short8x fqr[2], fqi[2], fqrn[2];
#pragma unroll
    for (int ks = 0; ks < 2; ks++) {
      fqr[ks] = *(const short8x*)(Qr + bhoff + (size_t)(qrow0 + l15) * DKK + ks * 32 + quad * 8);
      fqi[ks] = *(const short8x*)(Qi + bhoff + (size_t)(qrow0 + l15) * DKK + ks * 32 + quad * 8);
      fqrn[ks] = negbf(fqr[ks]);
    }
    float mr[4], li[4];
#pragma unroll
    for (int r = 0; r < 4; r++) {
      int s = qrow0 + quad * 4 + r;
      mr[r] = Mrow[(size_t)(b * HH + h) * SS + s];
      li[r] = 1.0f / Lrow[(size_t)(b * HH + h) * SS + s];
    }
    const int4* gkr = (const int4*)(Kr + bhoff + (size_t)(kt + srow) * DKK + sseg);
    const int4* gki = (const int4*)(Ki + bhoff + (size_t)(kt + srow) * DKK + sseg);
    int4 kr0 = gkr[0], kr1 = gkr[1], ki0 = gki[0], ki1 = gki[1];
    __syncthreads();
    *(int4*)&KsR[srow][sseg] = kr0;  *(int4*)&KsR[srow][sseg + 8] = kr1;
    *(int4*)&KsI[srow][sseg] = ki0;  *(int4*)&KsI[srow][sseg + 8] = ki1;
    __syncthreads();
#pragma unroll
    for (int nb = 0; nb < 4; nb++) {
      short8x bkr0 = *(const short8x*)&KsR[nb * 16 + l15][quad * 8];
      short8x bkr1 = *(const short8x*)&KsR[nb * 16 + l15][32 + quad * 8];
      short8x bki0 = *(const short8x*)&KsI[nb * 16 + l15][quad * 8];
      short8x bki1 = *(const short8x*)&KsI[nb * 16 + l15][32 + quad * 8];
      f32x4 sr = {0.f, 0.f, 0.f, 0.f}, si = {0.f, 0.f, 0.f, 0.f};
      sr = mfma16(fqr[0], bkr0, sr);  sr = mfma16(fqr[1], bkr1, sr);
      sr = mfma16(fqi[0], bki0, sr);  sr = mfma16(fqi[1], bki1, sr);
      si = mfma16(fqi[0], bkr0, si);  si = mfma16(fqi[1], bkr1, si);
      si = mfma16(fqrn[0], bki0, si); si = mfma16(fqrn[1], bki1, si);
#pragma unroll
      for (int r = 0; r < 4; r++) {
        float srv = sr[r] * scale;
        float siv = si[r] * scale;
        float r2 = srv * srv + siv * siv;
        float inv = rsqrtf(r2);
        float sc = (r2 * inv + 0.3f * srv * inv) * scale;
        float p = mk[nb] ? __expf(sc - mr[r]) * li[r] : 0.0f;
        psum[nb][r] += p;
      }
    }
  }
#pragma unroll
  for (int nb = 0; nb < 4; nb++)
#pragma unroll
    for (int r = 0; r < 4; r++) {
      int qrow = qrow0 + quad * 4 + r;
      out2[((size_t)b * SS + qrow) * SS + kt + nb * 16 + l15] = psum[nb][r] * 0.0625f;
    }
}

extern "C" void kernel_launch(void* const* d_in, const int* in_sizes, int n_in,
                              void* d_out, int out_size, void* d_ws, size_t ws_size,
                              hipStream_t stream) {
  const float* z_real = (const float*)d_in[0];
  const float* z_imag = (const float*)d_in[1];
  const float* Wq_r = (const float*)d_in[2];
  const float* Wq_i = (const float*)d_in[3];
  const float* Wk_r = (const float*)d_in[4];
  const float* Wk_i = (const float*)d_in[5];
  const float* Wv   = (const float*)d_in[6];
  const float* Wo_w = (const float*)d_in[7];
  const float* Wo_b = (const float*)d_in[8];
  const int*   mask = (const int*)d_in[9];
  char* ws = (char*)d_ws;

  // ws layout (bytes)
  constexpr size_t QKV_BYTES = (size_t)BB * HH * SS * DKK * 2;  // 8 MB each
  unsigned short* Qr   = (unsigned short*)(ws + 0);
  unsigned short* Qi   = (unsigned short*)(ws + QKV_BYTES);
  unsigned short* Kr   = (unsigned short*)(ws + 2 * QKV_BYTES);
  unsigned short* Ki   = (unsigned short*)(ws + 3 * QKV_BYTES);
  unsigned short* VT   = (unsigned short*)(ws + 4 * QKV_BYTES);
  unsigned short* ctx  = (unsigned short*)(ws + 5 * QKV_BYTES);              // 4096x1024 bf16 (8 MB)
  unsigned short* WcatT= (unsigned short*)(ws + 6 * QKV_BYTES);              // 5120x2048 bf16 (20 MB)
  unsigned short* WoT  = (unsigned short*)(ws + 6 * QKV_BYTES + 20971520);   // 1024x1024 bf16 (2 MB)
  unsigned short* Xcat = (unsigned short*)(ws + 6 * QKV_BYTES + 23068672);   // 4096x2048 bf16 (16 MB)
  float* Mrow = (float*)(ws + 6 * QKV_BYTES + 39845888);                     // 32*2048 f32
  float* Lrow = (float*)(ws + 6 * QKV_BYTES + 39845888 + 262144);

  float* out  = (float*)d_out;
  float* out2 = out + (size_t)BB * SS * DD;

  pack_w_kernel<<<dim3(45056), dim3(256), 0, stream>>>(Wq_r, Wq_i, Wk_r, Wk_i, Wv, Wo_w, WcatT, WoT);
  pack_x_kernel<<<dim3(32768), dim3(256), 0, stream>>>(z_real, z_imag, Xcat);
  gemm_proj_kernel<<<dim3(32, 40), dim3(256), 0, stream>>>(Xcat, WcatT, Qr, Qi, Kr, Ki, VT);
  flash_kernel<<<dim3(16, 16, 2), dim3(256), 0, stream>>>(Qr, Qi, Kr, Ki, VT, mask, ctx, Mrow, Lrow);
  gemm_out_kernel<<<dim3(32, 8), dim3(256), 0, stream>>>(ctx, WoT, Wo_b, out);
  probsmean_kernel<<<dim3(32, 32, 2), dim3(256), 0, stream>>>(Qr, Qi, Kr, Ki, mask, Mrow, Lrow, out2);
}

// Round 2
// 839.184 us; speedup vs baseline: 1.0364x; 1.0364x over previous
//
#include <hip/hip_runtime.h>
#include <cstdint>
#include <cstddef>

#define BB 2
#define SS 2048
#define DD 1024
#define HH 16
#define DKK 64

typedef __attribute__((ext_vector_type(8))) short short8x;
typedef __attribute__((ext_vector_type(4))) float f32x4;

__device__ __forceinline__ unsigned short f2b(float f) {
  union { float f; unsigned u; } v; v.f = f;
  unsigned r = (v.u + 0x7fffu + ((v.u >> 16) & 1u)) >> 16;  // RNE
  return (unsigned short)r;
}

__device__ __forceinline__ f32x4 mfma16(short8x a, short8x b, f32x4 c) {
  return __builtin_amdgcn_mfma_f32_16x16x32_bf16(a, b, c, 0, 0, 0);
}

__device__ __forceinline__ short8x negbf(short8x a) {
  short8x r;
#pragma unroll
  for (int j = 0; j < 8; j++) r[j] = (short)(a[j] ^ (short)0x8000);
  return r;
}

// ---------------- pack weights: WcatT[5120][2048] = [[Wq_r,Wq_i,Wk_r,Wk_i,Wv],[-Wq_i,Wq_r,-Wk_i,Wk_r,0]]^T (bf16)
//                  WoT[1024][1024] = Wo^T (bf16)
__global__ void pack_w_kernel(const float* __restrict__ Wq_r, const float* __restrict__ Wq_i,
                              const float* __restrict__ Wk_r, const float* __restrict__ Wk_i,
                              const float* __restrict__ Wv, const float* __restrict__ Wo,
                              unsigned short* __restrict__ WcatT, unsigned short* __restrict__ WoT) {
  int gid = blockIdx.x * 256 + threadIdx.x;
  if (gid < 5120 * 2048) {
    int k = gid & 2047;
    int n = gid >> 11;
    int q = n >> 10, j = n & 1023;
    float v;
    if (k < 1024) {
      const float* src = (q == 0) ? Wq_r : (q == 1) ? Wq_i : (q == 2) ? Wk_r : (q == 3) ? Wk_i : Wv;
      v = src[k * 1024 + j];
    } else {
      int k2 = k - 1024;
      if (q == 0)      v = -Wq_i[k2 * 1024 + j];
      else if (q == 1) v =  Wq_r[k2 * 1024 + j];
      else if (q == 2) v = -Wk_i[k2 * 1024 + j];
      else if (q == 3) v =  Wk_r[k2 * 1024 + j];
      else             v = 0.0f;
    }
    WcatT[gid] = f2b(v);
  } else {
    int g2 = gid - 5120 * 2048;            // n*1024 + k
    int k = g2 & 1023, n = g2 >> 10;
    WoT[g2] = f2b(Wo[k * 1024 + n]);
  }
}

// ---------------- pack X: Xcat[4096][2048] = [z_real | z_imag] (bf16)
__global__ void pack_x_kernel(const float* __restrict__ zr, const float* __restrict__ zi,
                              unsigned short* __restrict__ X) {
  int gid = blockIdx.x * 256 + threadIdx.x;  // 4096*2048
  int k = gid & 2047, m = gid >> 11;
  float v = (k < 1024) ? zr[m * 1024 + k] : zi[m * 1024 + (k - 1024)];
  X[gid] = f2b(v);
}

// ---------------- projection GEMM: C = Xcat @ WcatT^T, M=4096 N=5120 K=2048; epilogue routes to Q/K (bf16,[BH][S][DK]) and V^T ([BH][DK][S])
__global__ __launch_bounds__(256, 2) void gemm_proj_kernel(
    const unsigned short* __restrict__ A, const unsigned short* __restrict__ Bt,
    unsigned short* __restrict__ Qr, unsigned short* __restrict__ Qi,
    unsigned short* __restrict__ Kr, unsigned short* __restrict__ Ki,
    unsigned short* __restrict__ VT) {
  constexpr int K = 2048;
  __shared__ __attribute__((aligned(16))) unsigned short As[128][40];
  __shared__ __attribute__((aligned(16))) unsigned short Bs[128][40];
  const int tid = threadIdx.x;
  const int m0 = blockIdx.x * 128;
  const int n0 = blockIdx.y * 128;
  const int lane = tid & 63, wid = tid >> 6;
  const int l15 = lane & 15, quad = lane >> 4;
  const int wm = (wid & 1) * 64, wn = (wid >> 1) * 64;
  const int lrow = tid >> 1, lseg = (tid & 1) * 16;
  f32x4 acc[4][4] = {};
  const int4* ga = (const int4*)(A + (size_t)(m0 + lrow) * K + lseg);
  const int4* gb = (const int4*)(Bt + (size_t)(n0 + lrow) * K + lseg);
  for (int k0 = 0; k0 < K; k0 += 32) {
    int4 a0 = ga[0], a1 = ga[1];
    int4 b0 = gb[0], b1 = gb[1];
    __syncthreads();
    *(int4*)&As[lrow][lseg] = a0;  *(int4*)&As[lrow][lseg + 8] = a1;
    *(int4*)&Bs[lrow][lseg] = b0;  *(int4*)&Bs[lrow][lseg + 8] = b1;
    __syncthreads();
    short8x af[4], bfr[4];
#pragma unroll
    for (int i = 0; i < 4; i++) af[i]  = *(const short8x*)&As[wm + i * 16 + l15][quad * 8];
#pragma unroll
    for (int i = 0; i < 4; i++) bfr[i] = *(const short8x*)&Bs[wn + i * 16 + l15][quad * 8];
#pragma unroll
    for (int mi = 0; mi < 4; mi++)
#pragma unroll
      for (int ni = 0; ni < 4; ni++)
        acc[mi][ni] = mfma16(af[mi], bfr[ni], acc[mi][ni]);
    ga += 4; gb += 4;
  }
#pragma unroll
  for (int mi = 0; mi < 4; mi++) {
#pragma unroll
    for (int ni = 0; ni < 4; ni++) {
      int gn = n0 + wn + ni * 16 + l15;
#pragma unroll
      for (int r = 0; r < 4; r++) {
        int gm = m0 + wm + mi * 16 + quad * 4 + r;
        int b = gm >> 11, s = gm & 2047;
        unsigned short bv = f2b(acc[mi][ni][r]);
        if (gn < 4096) {
          int which = gn >> 10, j = gn & 1023, h = j >> 6, dk = j & 63;
          unsigned short* dst = (which == 0) ? Qr : (which == 1) ? Qi : (which == 2) ? Kr : Ki;
          dst[(((size_t)(b * HH + h)) * SS + s) * DKK + dk] = bv;
        } else {
          int j = gn - 4096, h = j >> 6, dk = j & 63;
          VT[(((size_t)(b * HH + h)) * DKK + dk) * SS + s] = bv;
        }
      }
    }
  }
}

// ---------------- flash attention fwd: per (b,h,qtile=128); online softmax; writes ctx (bf16 [B][S][D]) and row m,l
__global__ __launch_bounds__(256, 2) void flash_kernel(
    const unsigned short* __restrict__ Qr, const unsigned short* __restrict__ Qi,
    const unsigned short* __restrict__ Kr, const unsigned short* __restrict__ Ki,
    const unsigned short* __restrict__ VT, const int* __restrict__ mask,
    unsigned short* __restrict__ ctx, float* __restrict__ Mrow, float* __restrict__ Lrow) {
  __shared__ __attribute__((aligned(16))) unsigned short KsR[64][72];
  __shared__ __attribute__((aligned(16))) unsigned short KsI[64][72];
  __shared__ __attribute__((aligned(16))) unsigned short Vs[64][72];
  __shared__ __attribute__((aligned(16))) unsigned short Ps[4][32][72];
  const int tid = threadIdx.x;
  const int lane = tid & 63, wid = tid >> 6;
  const int l15 = lane & 15, quad = lane >> 4;
  const int qt = blockIdx.x * 128;
  const int h = blockIdx.y, b = blockIdx.z;
  const size_t bhoff = (size_t)(b * HH + h) * SS * DKK;
  const float scale = 0.125f;
  // Q fragments for this wave's 32 rows (2 m-blocks x 2 k-steps), kept in regs
  short8x fqr[2][2], fqi[2][2], fqrn[2][2];
#pragma unroll
  for (int mb = 0; mb < 2; mb++) {
    int row = qt + wid * 32 + mb * 16 + l15;
#pragma unroll
    for (int ks = 0; ks < 2; ks++) {
      fqr[mb][ks] = *(const short8x*)(Qr + bhoff + (size_t)row * DKK + ks * 32 + quad * 8);
      fqi[mb][ks] = *(const short8x*)(Qi + bhoff + (size_t)row * DKK + ks * 32 + quad * 8);
      fqrn[mb][ks] = negbf(fqr[mb][ks]);
    }
  }
  const int srow = tid >> 2, sseg = (tid & 3) * 16;
  float mrun[2][4], lrun[2][4];
  f32x4 ctxacc[2][4] = {};
#pragma unroll
  for (int mb = 0; mb < 2; mb++)
#pragma unroll
    for (int r = 0; r < 4; r++) { mrun[mb][r] = -3.0e38f; lrun[mb][r] = 0.0f; }

  for (int kt = 0; kt < SS; kt += 64) {
    const int4* gkr = (const int4*)(Kr + bhoff + (size_t)(kt + srow) * DKK + sseg);
    const int4* gki = (const int4*)(Ki + bhoff + (size_t)(kt + srow) * DKK + sseg);
    const int4* gv  = (const int4*)(VT + bhoff + (size_t)srow * SS + kt + sseg);
    int4 kr0 = gkr[0], kr1 = gkr[1];
    int4 ki0 = gki[0], ki1 = gki[1];
    int4 v0 = gv[0],  v1 = gv[1];
    int mk[4];
#pragma unroll
    for (int nb = 0; nb < 4; nb++) mk[nb] = mask[b * SS + kt + nb * 16 + l15];
    __syncthreads();
    *(int4*)&KsR[srow][sseg] = kr0;  *(int4*)&KsR[srow][sseg + 8] = kr1;
    *(int4*)&KsI[srow][sseg] = ki0;  *(int4*)&KsI[srow][sseg + 8] = ki1;
    *(int4*)&Vs[srow][sseg]  = v0;   *(int4*)&Vs[srow][sseg + 8]  = v1;
    __syncthreads();
    // scores: Sr = QrKr^T + QiKi^T ; Si = QiKr^T - QrKi^T
    f32x4 asr[2][4], asi[2][4];
#pragma unroll
    for (int nb = 0; nb < 4; nb++) {
      short8x bkr0 = *(const short8x*)&KsR[nb * 16 + l15][quad * 8];
      short8x bkr1 = *(const short8x*)&KsR[nb * 16 + l15][32 + quad * 8];
      short8x bki0 = *(const short8x*)&KsI[nb * 16 + l15][quad * 8];
      short8x bki1 = *(const short8x*)&KsI[nb * 16 + l15][32 + quad * 8];
#pragma unroll
      for (int mb = 0; mb < 2; mb++) {
        f32x4 sr = {0.f, 0.f, 0.f, 0.f}, si = {0.f, 0.f, 0.f, 0.f};
        sr = mfma16(fqr[mb][0], bkr0, sr);  sr = mfma16(fqr[mb][1], bkr1, sr);
        sr = mfma16(fqi[mb][0], bki0, sr);  sr = mfma16(fqi[mb][1], bki1, sr);
        si = mfma16(fqi[mb][0], bkr0, si);  si = mfma16(fqi[mb][1], bkr1, si);
        si = mfma16(fqrn[mb][0], bki0, si); si = mfma16(fqrn[mb][1], bki1, si);
        asr[mb][nb] = sr; asi[mb][nb] = si;
      }
    }
    // hybrid score epilogue (in-place into asr)
#pragma unroll
    for (int mb = 0; mb < 2; mb++)
#pragma unroll
      for (int nb = 0; nb < 4; nb++)
#pragma unroll
        for (int r = 0; r < 4; r++) {
          float srv = asr[mb][nb][r] * scale;
          float siv = asi[mb][nb][r] * scale;
          float r2 = srv * srv + siv * siv;
          float inv = rsqrtf(r2);
          float sc = (r2 * inv + 0.3f * srv * inv) * scale;
          asr[mb][nb][r] = mk[nb] ? sc : -1e9f;
        }
    // online softmax update per row
#pragma unroll
    for (int mb = 0; mb < 2; mb++)
#pragma unroll
      for (int r = 0; r < 4; r++) {
        float rm = fmaxf(fmaxf(asr[mb][0][r], asr[mb][1][r]), fmaxf(asr[mb][2][r], asr[mb][3][r]));
#pragma unroll
        for (int off = 1; off < 16; off <<= 1) rm = fmaxf(rm, __shfl_xor(rm, off, 64));
        float mnew = fmaxf(mrun[mb][r], rm);
        float al = __expf(mrun[mb][r] - mnew);
        mrun[mb][r] = mnew;
        float ps = 0.f;
#pragma unroll
        for (int nb = 0; nb < 4; nb++) {
          float p = __expf(asr[mb][nb][r] - mnew);
          Ps[wid][mb * 16 + quad * 4 + r][nb * 16 + l15] = f2b(p);
          ps += p;
        }
#pragma unroll
        for (int off = 1; off < 16; off <<= 1) ps += __shfl_xor(ps, off, 64);
        lrun[mb][r] = lrun[mb][r] * al + ps;
#pragma unroll
        for (int db = 0; db < 4; db++) ctxacc[mb][db][r] *= al;
      }
    // PV: ctx += P @ V   (P from per-wave LDS in A-layout; V^T tile as B-operand)
#pragma unroll
    for (int ks = 0; ks < 2; ks++)
#pragma unroll
      for (int db = 0; db < 4; db++) {
        short8x bv = *(const short8x*)&Vs[db * 16 + l15][ks * 32 + quad * 8];
#pragma unroll
        for (int mb = 0; mb < 2; mb++) {
          short8x ap = *(const short8x*)&Ps[wid][mb * 16 + l15][ks * 32 + quad * 8];
          ctxacc[mb][db] = mfma16(ap, bv, ctxacc[mb][db]);
        }
      }
  }
  // finalize
#pragma unroll
  for (int mb = 0; mb < 2; mb++)
#pragma unroll
    for (int r = 0; r < 4; r++) {
      int s = qt + wid * 32 + mb * 16 + quad * 4 + r;
      float linv = 1.0f / lrun[mb][r];
#pragma unroll
      for (int db = 0; db < 4; db++)
        ctx[((size_t)b * SS + s) * DD + h * DKK + db * 16 + l15] = f2b(ctxacc[mb][db][r] * linv);
      if (l15 == 0) {
        Mrow[(size_t)(b * HH + h) * SS + s] = mrun[mb][r];
        Lrow[(size_t)(b * HH + h) * SS + s] = lrun[mb][r];
      }
    }
}

// ---------------- output GEMM: out = ctx @ WoT^T + bias, M=4096 N=1024 K=1024 (fp32 out)
__global__ __launch_bounds__(256, 2) void gemm_out_kernel(
    const unsigned short* __restrict__ A, const unsigned short* __restrict__ Bt,
    const float* __restrict__ bias, float* __restrict__ out) {
  constexpr int K = 1024;
  __shared__ __attribute__((aligned(16))) unsigned short As[128][40];
  __shared__ __attribute__((aligned(16))) unsigned short Bs[128][40];
  const int tid = threadIdx.x;
  const int m0 = blockIdx.x * 128;
  const int n0 = blockIdx.y * 128;
  const int lane = tid & 63, wid = tid >> 6;
  const int l15 = lane & 15, quad = lane >> 4;
  const int wm = (wid & 1) * 64, wn = (wid >> 1) * 64;
  const int lrow = tid >> 1, lseg = (tid & 1) * 16;
  f32x4 acc[4][4] = {};
  const int4* ga = (const int4*)(A + (size_t)(m0 + lrow) * K + lseg);
  const int4* gb = (const int4*)(Bt + (size_t)(n0 + lrow) * K + lseg);
  for (int k0 = 0; k0 < K; k0 += 32) {
    int4 a0 = ga[0], a1 = ga[1];
    int4 b0 = gb[0], b1 = gb[1];
    __syncthreads();
    *(int4*)&As[lrow][lseg] = a0;  *(int4*)&As[lrow][lseg + 8] = a1;
    *(int4*)&Bs[lrow][lseg] = b0;  *(int4*)&Bs[lrow][lseg + 8] = b1;
    __syncthreads();
    short8x af[4], bfr[4];
#pragma unroll
    for (int i = 0; i < 4; i++) af[i]  = *(const short8x*)&As[wm + i * 16 + l15][quad * 8];
#pragma unroll
    for (int i = 0; i < 4; i++) bfr[i] = *(const short8x*)&Bs[wn + i * 16 + l15][quad * 8];
#pragma unroll
    for (int mi = 0; mi < 4; mi++)
#pragma unroll
      for (int ni = 0; ni < 4; ni++)
        acc[mi][ni] = mfma16(af[mi], bfr[ni], acc[mi][ni]);
    ga += 4; gb += 4;
  }
#pragma unroll
  for (int mi = 0; mi < 4; mi++)
#pragma unroll
    for (int ni = 0; ni < 4; ni++) {
      int gn = n0 + wn + ni * 16 + l15;
      float bv = bias[gn];
#pragma unroll
      for (int r = 0; r < 4; r++) {
        int gm = m0 + wm + mi * 16 + quad * 4 + r;
        out[(size_t)gm * 1024 + gn] = acc[mi][ni][r] + bv;
      }
    }
}

// ---------------- probs_mean: LDS-free recompute. Block = (b, qtile=64, ktile=64); wave = 16 q-rows.
// K fragments for the QK^H B-operand are contiguous 16B in [BH][S][DK] layout -> direct register loads,
// zero __syncthreads, zero bank conflicts; compiler pipelines the 16-head loop.
__global__ __launch_bounds__(256) void probsmean_kernel(
    const unsigned short* __restrict__ Qr, const unsigned short* __restrict__ Qi,
    const unsigned short* __restrict__ Kr, const unsigned short* __restrict__ Ki,
    const int* __restrict__ mask, const float* __restrict__ Mrow, const float* __restrict__ Lrow,
    float* __restrict__ out2) {
  const int tid = threadIdx.x, lane = tid & 63, wid = tid >> 6;
  const int l15 = lane & 15, quad = lane >> 4;
  const int qt = blockIdx.x * 64;
  const int kt = blockIdx.y * 64;
  const int b = blockIdx.z;
  const int qrow0 = qt + wid * 16;
  const float scale = 0.125f;
  int mk[4];
#pragma unroll
  for (int nb = 0; nb < 4; nb++) mk[nb] = mask[b * SS + kt + nb * 16 + l15];
  float psum[4][4] = {};  // [nb][r]
  for (int h = 0; h < HH; h++) {
    const size_t bhoff = (size_t)(b * HH + h) * SS * DKK;
    // Q fragments (A-operand): contiguous 16B per lane
    short8x fqr[2], fqi[2], fqrn[2];
#pragma unroll
    for (int ks = 0; ks < 2; ks++) {
      fqr[ks] = *(const short8x*)(Qr + bhoff + (size_t)(qrow0 + l15) * DKK + ks * 32 + quad * 8);
      fqi[ks] = *(const short8x*)(Qi + bhoff + (size_t)(qrow0 + l15) * DKK + ks * 32 + quad * 8);
      fqrn[ks] = negbf(fqr[ks]);
    }
    // K fragments (B-operand): direct from global, contiguous 16B per lane
    short8x bkr[4][2], bki[4][2];
#pragma unroll
    for (int nb = 0; nb < 4; nb++)
#pragma unroll
      for (int ks = 0; ks < 2; ks++) {
        bkr[nb][ks] = *(const short8x*)(Kr + bhoff + (size_t)(kt + nb * 16 + l15) * DKK + ks * 32 + quad * 8);
        bki[nb][ks] = *(const short8x*)(Ki + bhoff + (size_t)(kt + nb * 16 + l15) * DKK + ks * 32 + quad * 8);
      }
    // row stats: vectorized float4 (qrow0 + quad*4 is 16B-aligned)
    const float4 mv = *(const float4*)(Mrow + (size_t)(b * HH + h) * SS + qrow0 + quad * 4);
    const float4 lv = *(const float4*)(Lrow + (size_t)(b * HH + h) * SS + qrow0 + quad * 4);
    float mr[4], li[4];
    mr[0] = mv.x; mr[1] = mv.y; mr[2] = mv.z; mr[3] = mv.w;
    li[0] = 1.0f / lv.x; li[1] = 1.0f / lv.y; li[2] = 1.0f / lv.z; li[3] = 1.0f / lv.w;
#pragma unroll
    for (int nb = 0; nb < 4; nb++) {
      f32x4 sr = {0.f, 0.f, 0.f, 0.f}, si = {0.f, 0.f, 0.f, 0.f};
      sr = mfma16(fqr[0], bkr[nb][0], sr);  sr = mfma16(fqr[1], bkr[nb][1], sr);
      sr = mfma16(fqi[0], bki[nb][0], sr);  sr = mfma16(fqi[1], bki[nb][1], sr);
      si = mfma16(fqi[0], bkr[nb][0], si);  si = mfma16(fqi[1], bkr[nb][1], si);
      si = mfma16(fqrn[0], bki[nb][0], si); si = mfma16(fqrn[1], bki[nb][1], si);
#pragma unroll
      for (int r = 0; r < 4; r++) {
        float srv = sr[r] * scale;
        float siv = si[r] * scale;
        float r2 = srv * srv + siv * siv;
        float inv = rsqrtf(r2);
        float sc = (r2 * inv + 0.3f * srv * inv) * scale;
        float p = mk[nb] ? __expf(sc - mr[r]) * li[r] : 0.0f;
        psum[nb][r] += p;
      }
    }
  }
#pragma unroll
  for (int nb = 0; nb < 4; nb++)
#pragma unroll
    for (int r = 0; r < 4; r++) {
      int qrow = qrow0 + quad * 4 + r;
      out2[((size_t)b * SS + qrow) * SS + kt + nb * 16 + l15] = psum[nb][r] * 0.0625f;
    }
}

extern "C" void kernel_launch(void* const* d_in, const int* in_sizes, int n_in,
                              void* d_out, int out_size, void* d_ws, size_t ws_size,
                              hipStream_t stream) {
  const float* z_real = (const float*)d_in[0];
  const float* z_imag = (const float*)d_in[1];
  const float* Wq_r = (const float*)d_in[2];
  const float* Wq_i = (const float*)d_in[3];
  const float* Wk_r = (const float*)d_in[4];
  const float* Wk_i = (const float*)d_in[5];
  const float* Wv   = (const float*)d_in[6];
  const float* Wo_w = (const float*)d_in[7];
  const float* Wo_b = (const float*)d_in[8];
  const int*   mask = (const int*)d_in[9];
  char* ws = (char*)d_ws;

  // ws layout (bytes)
  constexpr size_t QKV_BYTES = (size_t)BB * HH * SS * DKK * 2;  // 8 MB each
  unsigned short* Qr   = (unsigned short*)(ws + 0);
  unsigned short* Qi   = (unsigned short*)(ws + QKV_BYTES);
  unsigned short* Kr   = (unsigned short*)(ws + 2 * QKV_BYTES);
  unsigned short* Ki   = (unsigned short*)(ws + 3 * QKV_BYTES);
  unsigned short* VT   = (unsigned short*)(ws + 4 * QKV_BYTES);
  unsigned short* ctx  = (unsigned short*)(ws + 5 * QKV_BYTES);              // 4096x1024 bf16 (8 MB)
  unsigned short* WcatT= (unsigned short*)(ws + 6 * QKV_BYTES);              // 5120x2048 bf16 (20 MB)
  unsigned short* WoT  = (unsigned short*)(ws + 6 * QKV_BYTES + 20971520);   // 1024x1024 bf16 (2 MB)
  unsigned short* Xcat = (unsigned short*)(ws + 6 * QKV_BYTES + 23068672);   // 4096x2048 bf16 (16 MB)
  float* Mrow = (float*)(ws + 6 * QKV_BYTES + 39845888);                     // 32*2048 f32
  float* Lrow = (float*)(ws + 6 * QKV_BYTES + 39845888 + 262144);

  float* out  = (float*)d_out;
  float* out2 = out + (size_t)BB * SS * DD;

  pack_w_kernel<<<dim3(45056), dim3(256), 0, stream>>>(Wq_r, Wq_i, Wk_r, Wk_i, Wv, Wo_w, WcatT, WoT);
  pack_x_kernel<<<dim3(32768), dim3(256), 0, stream>>>(z_real, z_imag, Xcat);
  gemm_proj_kernel<<<dim3(32, 40), dim3(256), 0, stream>>>(Xcat, WcatT, Qr, Qi, Kr, Ki, VT);
  flash_kernel<<<dim3(16, 16, 2), dim3(256), 0, stream>>>(Qr, Qi, Kr, Ki, VT, mask, ctx, Mrow, Lrow);
  gemm_out_kernel<<<dim3(32, 8), dim3(256), 0, stream>>>(ctx, WoT, Wo_b, out);
  probsmean_kernel<<<dim3(32, 32, 2), dim3(256), 0, stream>>>(Qr, Qi, Kr, Ki, mask, Mrow, Lrow, out2);
}